// Round 15
// baseline (159.177 us; speedup 1.0000x reference)
//
#include <hip/hip_runtime.h>

#define HEADS 8
#define DHEAD 40
#define SEQ   4096
#define BATCH 2
#define INNER 320
#define NBH   16
// softmax scale * log2(e), folded into Wq so p = exp2(s) is a single v_exp_f32
#define QSCALE ((float)(0.15811388300841897 * 1.4426950408889634))

typedef _Float16 f16;
typedef __attribute__((ext_vector_type(2)))  __fp16   fp16x2;  // cvt_pkrtz native type
typedef __attribute__((ext_vector_type(4)))  _Float16 half4;
typedef __attribute__((ext_vector_type(8)))  _Float16 half8;
typedef __attribute__((ext_vector_type(16))) float    f32x16;

#if __has_builtin(__builtin_amdgcn_exp2f)
#define EXP2F(x) __builtin_amdgcn_exp2f(x)
#else
#define EXP2F(x) exp2f(x)
#endif

#define MFMA16(a, b, c) __builtin_amdgcn_mfma_f32_32x32x16_f16(a, b, c, 0, 0, 0)

union H8 { half8 h8; fp16x2 p2[4]; uint4 u4; };

// ---------------------------------------------------------------------------
// Convert WEIGHTS only to f16: Wq|Wk|Wv -> wh [960][320] (Wq pre-scaled by
// QSCALE); Wout -> wouth. (Separate kernel defended in r13: fusing into
// B-staging regressed 6us.)
// ---------------------------------------------------------------------------
#define WQKV4 (3 * INNER * INNER / 4)     // 76800
#define WOUT4 (INNER * INNER / 4)         // 25600
#define WTOT4 (WQKV4 + WOUT4)             // 102400

__global__ __launch_bounds__(256)
void convert_kernel(const float* __restrict__ Wq,
                    const float* __restrict__ Wk,
                    const float* __restrict__ Wv,
                    const float* __restrict__ Wout,
                    f16* __restrict__ wh, f16* __restrict__ wouth)
{
    int i = blockIdx.x * 256 + threadIdx.x;
    if (i >= WTOT4) return;
    float4 v;
    f16* dst;
    float sc = 1.0f;
    if (i < WQKV4) {
        if (i < 25600)      { v = ((const float4*)Wq)[i]; sc = QSCALE; }
        else if (i < 51200) { v = ((const float4*)Wk)[i - 25600]; }
        else                { v = ((const float4*)Wv)[i - 51200]; }
        dst = wh + 4 * (size_t)i;
    } else {
        int j = i - WQKV4;
        v = ((const float4*)Wout)[j];
        dst = wouth + 4 * (size_t)j;
    }
    H8 u;
    u.p2[0] = __builtin_amdgcn_cvt_pkrtz(v.x * sc, v.y * sc);
    u.p2[1] = __builtin_amdgcn_cvt_pkrtz(v.z * sc, v.w * sc);
    *(uint2*)dst = make_uint2(u.u4.x, u.u4.y);
}

// ---------------------------------------------------------------------------
// Merged QKV projection, fp16 MFMA (r7 inner loop, defended 3x).
// v15: Q and K output layout changed [bh][s][40] -> [b][s][320] (col =
// h*40+d, the y-layout). The q/k scatter then writes CONSECUTIVE cols for
// consecutive lanes -> contiguous 64B store segments instead of ~64
// scattered 2B lines per wave-store (the last unexamined phase; est.
// 5-10us of uncoalesced-store tax + L2 write amplification). No h/dd
// division needed. V path unchanged.
// ---------------------------------------------------------------------------
#define QSTR 72

__global__ __launch_bounds__(256)
void qkv_gemm_kernel(const float* __restrict__ x, const f16* __restrict__ wh,
                     f16* __restrict__ q, f16* __restrict__ k,
                     f16* __restrict__ vt)
{
    __shared__ f16 lds[(64 + 192) * QSTR];   // As [64][72] + Bs [192][72] = 36864 B
    f16* As = lds;
    f16* Bs = lds + 64 * QSTR;

    const int tid = threadIdx.x;
    const int nb0 = blockIdx.x * 64;
    const int m0  = blockIdx.y * 64;
    const int wave = tid >> 6, lane = tid & 63, m = lane & 31, half = lane >> 5;
    const int mw = wave >> 1, nw = wave & 1;

    f32x16 acc[3];
    #pragma unroll
    for (int i = 0; i < 16; i++) { acc[0][i] = 0.f; acc[1][i] = 0.f; acc[2][i] = 0.f; }

    for (int k0 = 0; k0 < 320; k0 += 64) {
        __syncthreads();
        #pragma unroll
        for (int u = 0; u < 2; u++) {        // A: 64r x 64k, fp32 src + cvt
            int idx = tid + 256 * u;
            int r = idx >> 3, c8 = idx & 7;
            const float* xr = &x[(size_t)(m0 + r) * 320 + k0 + c8 * 8];
            float4 v0 = *(const float4*)xr;
            float4 v1 = *(const float4*)(xr + 4);
            H8 hh;
            hh.p2[0] = __builtin_amdgcn_cvt_pkrtz(v0.x, v0.y);
            hh.p2[1] = __builtin_amdgcn_cvt_pkrtz(v0.z, v0.w);
            hh.p2[2] = __builtin_amdgcn_cvt_pkrtz(v1.x, v1.y);
            hh.p2[3] = __builtin_amdgcn_cvt_pkrtz(v1.z, v1.w);
            *(uint4*)&As[r * QSTR + c8 * 8] = hh.u4;
        }
        #pragma unroll
        for (int u = 0; u < 6; u++) {        // B: 192r x 64k = 1536 uint4
            int idx = tid + 256 * u;
            int r = idx >> 3, c8 = idx & 7;
            int wr = (r >> 6) * 320 + nb0 + (r & 63);
            *(uint4*)&Bs[r * QSTR + c8 * 8] =
                *(const uint4*)&wh[(size_t)wr * 320 + k0 + c8 * 8];
        }
        __syncthreads();
        #pragma unroll
        for (int c = 0; c < 4; c++) {
            half8 a = *(const half8*)&As[(mw * 32 + m) * QSTR + c * 16 + half * 8];
            #pragma unroll
            for (int t = 0; t < 3; t++) {
                half8 bf = *(const half8*)&Bs[(nw * 96 + t * 32 + m) * QSTR + c * 16 + half * 8];
                acc[t] = MFMA16(a, bf, acc[t]);
            }
        }
    }

    const int b = m0 >> 12, s0 = m0 & 4095;

    // q / k scatter (subtiles st = nw*3+t < 4), coalesced [b][s][320] layout:
    // lanes m -> consecutive cols -> contiguous 64B segments per half-wave
    #pragma unroll
    for (int t = 0; t < 3; t++) {
        int st = nw * 3 + t;
        if (st < 4) {
            f16* dst = (st < 2) ? q : k;
            int col = nb0 + (st & 1) * 32 + m;
            #pragma unroll
            for (int reg = 0; reg < 16; reg++) {
                int crow = 4 * half + (reg & 3) + 8 * (reg >> 2);
                int mg = m0 + mw * 32 + crow;
                int bb = mg >> 12, s = mg & 4095;
                dst[((size_t)bb * SEQ + s) * INNER + col] = (f16)acc[t][reg];
            }
        }
    }

    // v transpose: subtiles st 4,5 (nw==1, t=1,2) -> Ct [64 vcol][72]
    __syncthreads();
    f16* Ct = lds;
    if (nw == 1) {
        #pragma unroll
        for (int t = 1; t < 3; t++) {
            int vr0 = (t - 1) * 32 + m;
            #pragma unroll
            for (int g = 0; g < 4; g++) {
                half4 hh;
                hh.x = (f16)acc[t][4 * g + 0]; hh.y = (f16)acc[t][4 * g + 1];
                hh.z = (f16)acc[t][4 * g + 2]; hh.w = (f16)acc[t][4 * g + 3];
                *(half4*)&Ct[vr0 * QSTR + mw * 32 + 8 * g + 4 * half] = hh;
            }
        }
    }
    __syncthreads();
    #pragma unroll
    for (int u = 0; u < 4; u++) {            // 64 rl x 16 c4 = 1024 uint2
        int idx = tid + 256 * u;
        int rl = idx >> 4, c4 = idx & 15;
        int col = nb0 + rl;
        int h  = (col * 205) >> 13;
        int dd = col - h * 40;
        int w4 = c4 & 3;
        int c4p = (c4 & ~3) | ((w4 == 1) ? 2 : (w4 == 2) ? 1 : w4);
        *(uint2*)&vt[((size_t)(b * 8 + h) * DHEAD + dd) * SEQ + s0 + c4p * 4] =
            *(const uint2*)&Ct[rl * QSTR + c4 * 4];
    }
}

// ---------------------------------------------------------------------------
// Flash attention (r10 pipeline, session-best): deferred-PV, iter j:
// stage(j) | barrier | S(j) | PV(j-1) | p = exp(S(j)). Carried state = p
// only (8 VGPR); 3-buffer LDS rotation (WAR-safe). Exact f32 kh-combine
// epilogue; ones-row at V d-row 40 gives row sums.
// v15 delta: Q/K now read from the [b][s][320] layout (base + h*40, row
// stride 320) -- pure addressing change, math identical.
// ---------------------------------------------------------------------------
__global__ __launch_bounds__(512, 4)
void attn_kernel(const f16* __restrict__ q, const f16* __restrict__ k,
                 const f16* __restrict__ vt, f16* __restrict__ y)
{
    // staging 3 x 16384B = 49152B | epilogue f32 [128][66] = 33792B (union)
    __shared__ __align__(16) unsigned char ldsbuf[49152];
    f16*   ldsh = (f16*)ldsbuf;
    float* ldsf = (float*)ldsbuf;

    const int tid = threadIdx.x;
    const int blk = blockIdx.x;
    const int xcd = blk & 7, slot = blk >> 3;        // XCD swizzle: 2 bh per XCD
    const int bh = xcd * 2 + (slot >> 5), qt = slot & 31;
    const int b = bh >> 3, h = bh & 7;
    const int q0 = qt * 128;
    const int wave = tid >> 6, lane = tid & 63, m = lane & 31, half = lane >> 5;
    const int qp = wave >> 1, kh = wave & 1;
    const int x7 = m & 7;

    // ---- one-time pads (swizzled slots, all THREE buffers)
    if (tid < 192) {                                  // K logical chunk 5 = 0
        int bsel = tid >> 6, r = tid & 63;
        *(uint4*)&ldsh[bsel * 8192 + r * 64 + 8 * (5 ^ (r & 7))] = make_uint4(0, 0, 0, 0);
    }
    {                                                 // V rows 40..63: 3 x 192 = 576
        int idx = tid;
        #pragma unroll
        for (int pass = 0; pass < 2; pass++) {
            if (pass == 0 || tid < 64) {
                int bsel = idx / 192;
                int j = idx - bsel * 192;
                int r = 40 + (j >> 3), c = j & 7;
                uint4 val = (r == 40) ? make_uint4(0x3C003C00u, 0x3C003C00u, 0x3C003C00u, 0x3C003C00u)
                                      : make_uint4(0, 0, 0, 0);
                *(uint4*)&ldsh[bsel * 8192 + 4096 + r * 64 + 8 * (c ^ (r & 7))] = val;
            }
            idx = 512 + tid;
        }
    }

    half8 zero8;
    #pragma unroll
    for (int j = 0; j < 8; j++) zero8[j] = (f16)0.0f;

    // ---- Q B-fragments: rows q0 + qp*32 + m, cols h*40.. (d 40..47 -> 0)
    half8 qa[3];
    {
        const f16* qb = q + ((size_t)b * SEQ + q0 + qp * 32 + m) * INNER + h * DHEAD;
        qa[0] = *(const half8*)&qb[half * 8];
        qa[1] = *(const half8*)&qb[16 + half * 8];
        qa[2] = (half == 1) ? zero8 : *(const half8*)&qb[32];
    }

    f32x16 O0, O1;
    #pragma unroll
    for (int i = 0; i < 16; i++) { O0[i] = 0.f; O1[i] = 0.f; }

    const f16* kb = k  + (size_t)b * SEQ * INNER + h * DHEAD;  // [s][320] rows
    const f16* vb = vt + (size_t)bh * DHEAD * SEQ;             // [d][SEQ], keys perm'd

    // ---- staging: 640 uint4 slots (K 320: r=idx/5,c=idx%5 / V 320:
    //      r=idx>>3,c=idx&7). Thread t does slot t; t<128 also slot 512+t.
    const bool aIsK = (tid < 320);
    int adst;
    size_t astep;
    const f16* aptr;
    if (aIsK) {
        int r = (tid * 205) >> 10, c = tid - r * 5;
        adst = r * 64 + 8 * (c ^ (r & 7));
        aptr = kb + (size_t)r * INNER + c * 8;
        astep = (size_t)64 * INNER;
    } else {
        int t = tid - 320;                            // 0..191 -> V rows 0..23
        int r = t >> 3, c = t & 7;
        adst = 4096 + r * 64 + 8 * (c ^ (r & 7));
        aptr = vb + (size_t)r * SEQ + c * 8;
        astep = 64;
    }
    const bool hasB = (tid < 128);
    int bdst = 0;
    const f16* bptr = vb;
    if (hasB) {                                       // V rows 24..39
        int t = 192 + tid;
        int r = t >> 3, c = t & 7;
        bdst = 4096 + r * 64 + 8 * (c ^ (r & 7));
        bptr = vb + (size_t)r * SEQ + c * 8;
    }

    // prefetch tile 0 into registers
    uint4 sA = *(const uint4*)aptr;
    uint4 sB = make_uint4(0, 0, 0, 0);
    if (hasB) sB = *(const uint4*)bptr;

    H8 p0, p1;                 // carried P of the previous tile
    int stg  = 0;              // buffer of current tile j
    int stgv = 0;              // buffer of tile j-1 (V source for deferred PV)

    // ---- peeled iteration j = 0: stage, S, exp (no PV yet)
    {
        *(uint4*)&ldsh[stg + adst] = sA;
        if (hasB) *(uint4*)&ldsh[stg + bdst] = sB;
        __syncthreads();
        aptr += astep; sA = *(const uint4*)aptr;
        if (hasB) { bptr += 64; sB = *(const uint4*)bptr; }

        half8 kf[3];
        #pragma unroll
        for (int c = 0; c < 3; c++)
            kf[c] = *(const half8*)&ldsh[stg + (kh * 32 + m) * 64 + 8 * ((2 * c + half) ^ x7)];
        f32x16 S;
        #pragma unroll
        for (int i = 0; i < 16; i++) S[i] = 0.f;
        __builtin_amdgcn_s_setprio(1);
        S = MFMA16(kf[0], qa[0], S);
        S = MFMA16(kf[1], qa[1], S);
        S = MFMA16(kf[2], qa[2], S);
        __builtin_amdgcn_s_setprio(0);
        #pragma unroll
        for (int g = 0; g < 4; g++) {
            p0.p2[g] = __builtin_amdgcn_cvt_pkrtz(EXP2F(S[2 * g]),     EXP2F(S[2 * g + 1]));
            p1.p2[g] = __builtin_amdgcn_cvt_pkrtz(EXP2F(S[8 + 2 * g]), EXP2F(S[9 + 2 * g]));
        }
        stg = 8192;
    }

    for (int j = 1; j < 64; ++j) {
        // stage tile j into buf(j%3)
        *(uint4*)&ldsh[stg + adst] = sA;
        if (hasB) *(uint4*)&ldsh[stg + bdst] = sB;
        __syncthreads();

        // prefetch tile j+1 (lands during this tile's compute)
        if (j < 63) {
            aptr += astep; sA = *(const uint4*)aptr;
            if (hasB) { bptr += 64; sB = *(const uint4*)bptr; }
        }

        // ---- S(j) from buf(stg)
        half8 kf[3];
        #pragma unroll
        for (int c = 0; c < 3; c++)
            kf[c] = *(const half8*)&ldsh[stg + (kh * 32 + m) * 64 + 8 * ((2 * c + half) ^ x7)];
        f32x16 S;
        #pragma unroll
        for (int i = 0; i < 16; i++) S[i] = 0.f;
        __builtin_amdgcn_s_setprio(1);
        S = MFMA16(kf[0], qa[0], S);
        S = MFMA16(kf[1], qa[1], S);
        S = MFMA16(kf[2], qa[2], S);
        __builtin_amdgcn_s_setprio(0);

        // ---- deferred PV(j-1) from buf(stgv): independent of exp(S) below,
        //      its MFMAs interleave with the exp burst and the S chain drain
        {
            const f16* Vb = &ldsh[stgv + 4096];
            half8 vf[2][2];
            #pragma unroll
            for (int c = 0; c < 2; c++) {
                vf[c][0] = *(const half8*)&Vb[m * 64        + 8 * ((4 * kh + 2 * c + half) ^ x7)];
                vf[c][1] = *(const half8*)&Vb[(32 + m) * 64 + 8 * ((4 * kh + 2 * c + half) ^ x7)];
            }
            __builtin_amdgcn_s_setprio(1);
            O0 = MFMA16(p0.h8, vf[0][0], O0);
            O1 = MFMA16(p0.h8, vf[0][1], O1);
            O0 = MFMA16(p1.h8, vf[1][0], O0);
            O1 = MFMA16(p1.h8, vf[1][1], O1);
            __builtin_amdgcn_s_setprio(0);
        }

        // ---- p = exp2(S(j))  (TRANS pipe; overlaps PV MFMAs above)
        #pragma unroll
        for (int g = 0; g < 4; g++) {
            p0.p2[g] = __builtin_amdgcn_cvt_pkrtz(EXP2F(S[2 * g]),     EXP2F(S[2 * g + 1]));
            p1.p2[g] = __builtin_amdgcn_cvt_pkrtz(EXP2F(S[8 + 2 * g]), EXP2F(S[9 + 2 * g]));
        }

        stgv = stg;
        stg = (stg == 16384) ? 0 : stg + 8192;
    }

    // ---- final PV (tile 63) from buf(stgv)
    {
        const f16* Vb = &ldsh[stgv + 4096];
        half8 vf[2][2];
        #pragma unroll
        for (int c = 0; c < 2; c++) {
            vf[c][0] = *(const half8*)&Vb[m * 64        + 8 * ((4 * kh + 2 * c + half) ^ x7)];
            vf[c][1] = *(const half8*)&Vb[(32 + m) * 64 + 8 * ((4 * kh + 2 * c + half) ^ x7)];
        }
        O0 = MFMA16(p0.h8, vf[0][0], O0);
        O1 = MFMA16(p0.h8, vf[0][1], O1);
        O0 = MFMA16(p1.h8, vf[1][0], O0);
        O1 = MFMA16(p1.h8, vf[1][1], O1);
    }

    // ---- combine key-halves (exact: unnormalized sums), normalize, store y
    __syncthreads();
    if (kh == 1) {
        #pragma unroll
        for (int reg = 0; reg < 16; reg++) {
            int row = 4 * half + (reg & 3) + 8 * (reg >> 2);
            ldsf[(qp * 32 + row) * 66 + m]      = O0[reg];
            ldsf[(qp * 32 + row) * 66 + 32 + m] = O1[reg];
        }
    }
    __syncthreads();
    if (kh == 0) {
        #pragma unroll
        for (int reg = 0; reg < 16; reg++) {
            int row = 4 * half + (reg & 3) + 8 * (reg >> 2);
            O0[reg] += ldsf[(qp * 32 + row) * 66 + m];
            O1[reg] += ldsf[(qp * 32 + row) * 66 + 32 + m];
        }
        #pragma unroll
        for (int reg = 0; reg < 16; reg++) {
            float l = __shfl(O1[reg], 8 + 32 * half, 64);
            float rinv = 1.0f / l;
            int row = 4 * half + (reg & 3) + 8 * (reg >> 2);
            f16* yr = y + ((size_t)b * SEQ + q0 + qp * 32 + row) * INNER + h * DHEAD;
            yr[m] = (f16)(O0[reg] * rinv);                 // d 0..31
            if (m < 8) yr[32 + m] = (f16)(O1[reg] * rinv); // d 32..39
        }
    }
}

// ---------------------------------------------------------------------------
// Output projection, fp16 MFMA: out = y @ Wout^T + bout, fp32 out.
// (r7 structure, verbatim)
// ---------------------------------------------------------------------------
#define ASTR 72

__global__ __launch_bounds__(256)
void out_proj_kernel(const f16* __restrict__ y, const f16* __restrict__ wouth,
                     const float* __restrict__ bout, float* __restrict__ out)
{
    __shared__ f16 lds[(128 + 64) * ASTR];
    f16* As = lds;
    f16* Bs = lds + 128 * ASTR;

    const int tid = threadIdx.x;
    const int m0 = blockIdx.y * 128;
    const int n0 = blockIdx.x * 64;
    const int wave = tid >> 6, lane = tid & 63, m = lane & 31, half = lane >> 5;

    f32x16 acc[2];
    #pragma unroll
    for (int i = 0; i < 16; i++) { acc[0][i] = 0.f; acc[1][i] = 0.f; }

    for (int k0 = 0; k0 < 320; k0 += 64) {
        __syncthreads();
        #pragma unroll
        for (int u = 0; u < 4; u++) {
            int idx = tid + 256 * u;
            int r = idx >> 3, c8 = idx & 7;
            *(uint4*)&As[r * ASTR + c8 * 8] =
                *(const uint4*)&y[(size_t)(m0 + r) * 320 + k0 + c8 * 8];
        }
        #pragma unroll
        for (int u = 0; u < 2; u++) {
            int idx = tid + 256 * u;
            int r = idx >> 3, c8 = idx & 7;
            *(uint4*)&Bs[r * ASTR + c8 * 8] =
                *(const uint4*)&wouth[(size_t)(n0 + r) * 320 + k0 + c8 * 8];
        }
        __syncthreads();
        #pragma unroll
        for (int c = 0; c < 4; c++) {
            half8 a  = *(const half8*)&As[(wave * 32 + m) * ASTR + c * 16 + half * 8];
            half8 b0 = *(const half8*)&Bs[m * ASTR + c * 16 + half * 8];
            half8 b1 = *(const half8*)&Bs[(32 + m) * ASTR + c * 16 + half * 8];
            acc[0] = MFMA16(a, b0, acc[0]);
            acc[1] = MFMA16(a, b1, acc[1]);
        }
    }

    #pragma unroll
    for (int nt = 0; nt < 2; nt++) {
        int n = n0 + nt * 32 + m;
        float bias = bout[n];
        #pragma unroll
        for (int reg = 0; reg < 16; reg++) {
            int crow = 4 * half + (reg & 3) + 8 * (reg >> 2);
            out[(size_t)(m0 + wave * 32 + crow) * 320 + n] = acc[nt][reg] + bias;
        }
    }
}

// ---------------------------------------------------------------------------
extern "C" void kernel_launch(void* const* d_in, const int* in_sizes, int n_in,
                              void* d_out, int out_size, void* d_ws, size_t ws_size,
                              hipStream_t stream)
{
    const float* x    = (const float*)d_in[0];
    const float* Wq   = (const float*)d_in[1];
    const float* Wk   = (const float*)d_in[2];
    const float* Wv   = (const float*)d_in[3];
    const float* Wout = (const float*)d_in[4];
    const float* bout = (const float*)d_in[5];
    float* out = (float*)d_out;

    unsigned char* ws = (unsigned char*)d_ws;
    f16* wh    = (f16*)(ws);                  //    614,400 B
    f16* wouth = (f16*)(ws +   614400);       //    204,800 B
    f16* qd    = (f16*)(ws +   819200);       //  5,242,880 B  [b][s][320]
    f16* kd    = (f16*)(ws +  6062080);       //  5,242,880 B  [b][s][320]
    f16* vtd   = (f16*)(ws + 11304960);       //  5,242,880 B  [bh][40][4096]
    f16* yd    = (f16*)(ws + 16547840);       //  5,242,880 B

    convert_kernel <<<400,          256, 0, stream>>>(Wq, Wk, Wv, Wout, wh, wouth);
    qkv_gemm_kernel<<<dim3(5, 128), 256, 0, stream>>>(x, wh, qd, kd, vtd);
    attn_kernel    <<<512,          512, 0, stream>>>(qd, kd, vtd, yd);
    out_proj_kernel<<<dim3(5, 64),  256, 0, stream>>>(yd, wouth, bout, out);
}

// Round 16
// 155.538 us; speedup vs baseline: 1.0234x; 1.0234x over previous
//
#include <hip/hip_runtime.h>

#define HEADS 8
#define DHEAD 40
#define SEQ   4096
#define BATCH 2
#define INNER 320
#define NBH   16
// softmax scale * log2(e), folded into Wq so p = exp2(s) is a single v_exp_f32
#define QSCALE ((float)(0.15811388300841897 * 1.4426950408889634))

typedef _Float16 f16;
typedef __attribute__((ext_vector_type(2)))  __fp16   fp16x2;  // cvt_pkrtz native type
typedef __attribute__((ext_vector_type(4)))  _Float16 half4;
typedef __attribute__((ext_vector_type(8)))  _Float16 half8;
typedef __attribute__((ext_vector_type(16))) float    f32x16;

#if __has_builtin(__builtin_amdgcn_exp2f)
#define EXP2F(x) __builtin_amdgcn_exp2f(x)
#else
#define EXP2F(x) exp2f(x)
#endif

#define MFMA16(a, b, c) __builtin_amdgcn_mfma_f32_32x32x16_f16(a, b, c, 0, 0, 0)

union H8 { half8 h8; fp16x2 p2[4]; uint4 u4; };

// ---------------------------------------------------------------------------
// Convert WEIGHTS only to f16: Wq|Wk|Wv -> wh [960][320] (Wq pre-scaled by
// QSCALE); Wout -> wouth. (Separate kernel defended in r13.)
// ---------------------------------------------------------------------------
#define WQKV4 (3 * INNER * INNER / 4)     // 76800
#define WOUT4 (INNER * INNER / 4)         // 25600
#define WTOT4 (WQKV4 + WOUT4)             // 102400

__global__ __launch_bounds__(256)
void convert_kernel(const float* __restrict__ Wq,
                    const float* __restrict__ Wk,
                    const float* __restrict__ Wv,
                    const float* __restrict__ Wout,
                    f16* __restrict__ wh, f16* __restrict__ wouth)
{
    int i = blockIdx.x * 256 + threadIdx.x;
    if (i >= WTOT4) return;
    float4 v;
    f16* dst;
    float sc = 1.0f;
    if (i < WQKV4) {
        if (i < 25600)      { v = ((const float4*)Wq)[i]; sc = QSCALE; }
        else if (i < 51200) { v = ((const float4*)Wk)[i - 25600]; }
        else                { v = ((const float4*)Wv)[i - 51200]; }
        dst = wh + 4 * (size_t)i;
    } else {
        int j = i - WQKV4;
        v = ((const float4*)Wout)[j];
        dst = wouth + 4 * (size_t)j;
    }
    H8 u;
    u.p2[0] = __builtin_amdgcn_cvt_pkrtz(v.x * sc, v.y * sc);
    u.p2[1] = __builtin_amdgcn_cvt_pkrtz(v.z * sc, v.w * sc);
    *(uint2*)dst = make_uint2(u.u4.x, u.u4.y);
}

// ---------------------------------------------------------------------------
// Merged QKV projection, fp16 MFMA (r7 structure, verbatim -- defended 4x:
// r3 prefetch, r9 gload_lds, r13 cvt-fusion, r15 store-layout all regressed).
// ---------------------------------------------------------------------------
#define QSTR 72

__global__ __launch_bounds__(256)
void qkv_gemm_kernel(const float* __restrict__ x, const f16* __restrict__ wh,
                     f16* __restrict__ q, f16* __restrict__ k,
                     f16* __restrict__ vt)
{
    __shared__ f16 lds[(64 + 192) * QSTR];   // As [64][72] + Bs [192][72] = 36864 B
    f16* As = lds;
    f16* Bs = lds + 64 * QSTR;

    const int tid = threadIdx.x;
    const int nb0 = blockIdx.x * 64;
    const int m0  = blockIdx.y * 64;
    const int wave = tid >> 6, lane = tid & 63, m = lane & 31, half = lane >> 5;
    const int mw = wave >> 1, nw = wave & 1;

    f32x16 acc[3];
    #pragma unroll
    for (int i = 0; i < 16; i++) { acc[0][i] = 0.f; acc[1][i] = 0.f; acc[2][i] = 0.f; }

    for (int k0 = 0; k0 < 320; k0 += 64) {
        __syncthreads();
        #pragma unroll
        for (int u = 0; u < 2; u++) {        // A: 64r x 64k, fp32 src + cvt
            int idx = tid + 256 * u;
            int r = idx >> 3, c8 = idx & 7;
            const float* xr = &x[(size_t)(m0 + r) * 320 + k0 + c8 * 8];
            float4 v0 = *(const float4*)xr;
            float4 v1 = *(const float4*)(xr + 4);
            H8 hh;
            hh.p2[0] = __builtin_amdgcn_cvt_pkrtz(v0.x, v0.y);
            hh.p2[1] = __builtin_amdgcn_cvt_pkrtz(v0.z, v0.w);
            hh.p2[2] = __builtin_amdgcn_cvt_pkrtz(v1.x, v1.y);
            hh.p2[3] = __builtin_amdgcn_cvt_pkrtz(v1.z, v1.w);
            *(uint4*)&As[r * QSTR + c8 * 8] = hh.u4;
        }
        #pragma unroll
        for (int u = 0; u < 6; u++) {        // B: 192r x 64k = 1536 uint4
            int idx = tid + 256 * u;
            int r = idx >> 3, c8 = idx & 7;
            int wr = (r >> 6) * 320 + nb0 + (r & 63);
            *(uint4*)&Bs[r * QSTR + c8 * 8] =
                *(const uint4*)&wh[(size_t)wr * 320 + k0 + c8 * 8];
        }
        __syncthreads();
        #pragma unroll
        for (int c = 0; c < 4; c++) {
            half8 a = *(const half8*)&As[(mw * 32 + m) * QSTR + c * 16 + half * 8];
            #pragma unroll
            for (int t = 0; t < 3; t++) {
                half8 bf = *(const half8*)&Bs[(nw * 96 + t * 32 + m) * QSTR + c * 16 + half * 8];
                acc[t] = MFMA16(a, bf, acc[t]);
            }
        }
    }

    const int b = m0 >> 12, s0 = m0 & 4095;

    // q / k scatter (subtiles st = nw*3+t < 4)
    #pragma unroll
    for (int t = 0; t < 3; t++) {
        int st = nw * 3 + t;
        if (st < 4) {
            f16* dst = (st < 2) ? q : k;
            int col = nb0 + (st & 1) * 32 + m;
            int h  = (col * 205) >> 13;          // == col/40 for col<328
            int dd = col - h * 40;
            #pragma unroll
            for (int reg = 0; reg < 16; reg++) {
                int crow = 4 * half + (reg & 3) + 8 * (reg >> 2);
                int mg = m0 + mw * 32 + crow;
                int bb = mg >> 12, s = mg & 4095;
                dst[((size_t)(bb * 8 + h) * SEQ + s) * DHEAD + dd] = (f16)acc[t][reg];
            }
        }
    }

    // v transpose: subtiles st 4,5 (nw==1, t=1,2) -> Ct [64 vcol][72]
    __syncthreads();
    f16* Ct = lds;
    if (nw == 1) {
        #pragma unroll
        for (int t = 1; t < 3; t++) {
            int vr0 = (t - 1) * 32 + m;
            #pragma unroll
            for (int g = 0; g < 4; g++) {
                half4 hh;
                hh.x = (f16)acc[t][4 * g + 0]; hh.y = (f16)acc[t][4 * g + 1];
                hh.z = (f16)acc[t][4 * g + 2]; hh.w = (f16)acc[t][4 * g + 3];
                *(half4*)&Ct[vr0 * QSTR + mw * 32 + 8 * g + 4 * half] = hh;
            }
        }
    }
    __syncthreads();
    #pragma unroll
    for (int u = 0; u < 4; u++) {            // 64 rl x 16 c4 = 1024 uint2
        int idx = tid + 256 * u;
        int rl = idx >> 4, c4 = idx & 15;
        int col = nb0 + rl;
        int h  = (col * 205) >> 13;
        int dd = col - h * 40;
        int w4 = c4 & 3;
        int c4p = (c4 & ~3) | ((w4 == 1) ? 2 : (w4 == 2) ? 1 : w4);
        *(uint2*)&vt[((size_t)(b * 8 + h) * DHEAD + dd) * SEQ + s0 + c4p * 4] =
            *(const uint2*)&Ct[rl * QSTR + c4 * 4];
    }
}

// ---------------------------------------------------------------------------
// Flash attention (r10 verbatim -- session-best attn): deferred-PV pipeline.
// iter j: stage(j) | barrier | S(j) | PV(j-1) | p = exp(S(j)). Carried
// state = p only (8 VGPR); 3-buffer LDS rotation (WAR-safe). Exact f32
// kh-combine epilogue; ones-row at V d-row 40 gives row sums.
// Closed: r8/r11 chain-carry (spill), r12 PV-hoist (neutral), r6 exp2-poly
// (TRANS already overlapped), r7 occupancy (insensitive), r15 layout (worse).
// ---------------------------------------------------------------------------
__global__ __launch_bounds__(512, 4)
void attn_kernel(const f16* __restrict__ q, const f16* __restrict__ k,
                 const f16* __restrict__ vt, f16* __restrict__ y)
{
    // staging 3 x 16384B = 49152B | epilogue f32 [128][66] = 33792B (union)
    __shared__ __align__(16) unsigned char ldsbuf[49152];
    f16*   ldsh = (f16*)ldsbuf;
    float* ldsf = (float*)ldsbuf;

    const int tid = threadIdx.x;
    const int blk = blockIdx.x;
    const int xcd = blk & 7, slot = blk >> 3;        // XCD swizzle: 2 bh per XCD
    const int bh = xcd * 2 + (slot >> 5), qt = slot & 31;
    const int b = bh >> 3, h = bh & 7;
    const int q0 = qt * 128;
    const int wave = tid >> 6, lane = tid & 63, m = lane & 31, half = lane >> 5;
    const int qp = wave >> 1, kh = wave & 1;
    const int x7 = m & 7;

    // ---- one-time pads (swizzled slots, all THREE buffers)
    if (tid < 192) {                                  // K logical chunk 5 = 0
        int bsel = tid >> 6, r = tid & 63;
        *(uint4*)&ldsh[bsel * 8192 + r * 64 + 8 * (5 ^ (r & 7))] = make_uint4(0, 0, 0, 0);
    }
    {                                                 // V rows 40..63: 3 x 192 = 576
        int idx = tid;
        #pragma unroll
        for (int pass = 0; pass < 2; pass++) {
            if (pass == 0 || tid < 64) {
                int bsel = idx / 192;
                int j = idx - bsel * 192;
                int r = 40 + (j >> 3), c = j & 7;
                uint4 val = (r == 40) ? make_uint4(0x3C003C00u, 0x3C003C00u, 0x3C003C00u, 0x3C003C00u)
                                      : make_uint4(0, 0, 0, 0);
                *(uint4*)&ldsh[bsel * 8192 + 4096 + r * 64 + 8 * (c ^ (r & 7))] = val;
            }
            idx = 512 + tid;
        }
    }

    half8 zero8;
    #pragma unroll
    for (int j = 0; j < 8; j++) zero8[j] = (f16)0.0f;

    // ---- Q B-fragments: rows q0 + qp*32 + m (d 40..47 -> 0)
    half8 qa[3];
    {
        const f16* qb = q + ((size_t)bh * SEQ + q0 + qp * 32 + m) * DHEAD;
        qa[0] = *(const half8*)&qb[half * 8];
        qa[1] = *(const half8*)&qb[16 + half * 8];
        qa[2] = (half == 1) ? zero8 : *(const half8*)&qb[32];
    }

    f32x16 O0, O1;
    #pragma unroll
    for (int i = 0; i < 16; i++) { O0[i] = 0.f; O1[i] = 0.f; }

    const f16* kb = k  + (size_t)bh * SEQ * DHEAD;   // [s][40]
    const f16* vb = vt + (size_t)bh * DHEAD * SEQ;   // [d][SEQ], keys perm'd

    // ---- staging: 640 uint4 slots (K 320: r=idx/5,c=idx%5 / V 320:
    //      r=idx>>3,c=idx&7). Thread t does slot t; t<128 also slot 512+t.
    const bool aIsK = (tid < 320);
    int adst, astep;
    const f16* aptr;
    if (aIsK) {
        int r = (tid * 205) >> 10, c = tid - r * 5;
        adst = r * 64 + 8 * (c ^ (r & 7));
        aptr = kb + (size_t)r * DHEAD + c * 8;
        astep = 64 * DHEAD;
    } else {
        int t = tid - 320;                            // 0..191 -> V rows 0..23
        int r = t >> 3, c = t & 7;
        adst = 4096 + r * 64 + 8 * (c ^ (r & 7));
        aptr = vb + (size_t)r * SEQ + c * 8;
        astep = 64;
    }
    const bool hasB = (tid < 128);
    int bdst = 0;
    const f16* bptr = vb;
    if (hasB) {                                       // V rows 24..39
        int t = 192 + tid;
        int r = t >> 3, c = t & 7;
        bdst = 4096 + r * 64 + 8 * (c ^ (r & 7));
        bptr = vb + (size_t)r * SEQ + c * 8;
    }

    // prefetch tile 0 into registers
    uint4 sA = *(const uint4*)aptr;
    uint4 sB = make_uint4(0, 0, 0, 0);
    if (hasB) sB = *(const uint4*)bptr;

    H8 p0, p1;                 // carried P of the previous tile
    int stg  = 0;              // buffer of current tile j
    int stgv = 0;              // buffer of tile j-1 (V source for deferred PV)

    // ---- peeled iteration j = 0: stage, S, exp (no PV yet)
    {
        *(uint4*)&ldsh[stg + adst] = sA;
        if (hasB) *(uint4*)&ldsh[stg + bdst] = sB;
        __syncthreads();
        aptr += astep; sA = *(const uint4*)aptr;
        if (hasB) { bptr += 64; sB = *(const uint4*)bptr; }

        half8 kf[3];
        #pragma unroll
        for (int c = 0; c < 3; c++)
            kf[c] = *(const half8*)&ldsh[stg + (kh * 32 + m) * 64 + 8 * ((2 * c + half) ^ x7)];
        f32x16 S;
        #pragma unroll
        for (int i = 0; i < 16; i++) S[i] = 0.f;
        __builtin_amdgcn_s_setprio(1);
        S = MFMA16(kf[0], qa[0], S);
        S = MFMA16(kf[1], qa[1], S);
        S = MFMA16(kf[2], qa[2], S);
        __builtin_amdgcn_s_setprio(0);
        #pragma unroll
        for (int g = 0; g < 4; g++) {
            p0.p2[g] = __builtin_amdgcn_cvt_pkrtz(EXP2F(S[2 * g]),     EXP2F(S[2 * g + 1]));
            p1.p2[g] = __builtin_amdgcn_cvt_pkrtz(EXP2F(S[8 + 2 * g]), EXP2F(S[9 + 2 * g]));
        }
        stg = 8192;
    }

    for (int j = 1; j < 64; ++j) {
        // stage tile j into buf(j%3)
        *(uint4*)&ldsh[stg + adst] = sA;
        if (hasB) *(uint4*)&ldsh[stg + bdst] = sB;
        __syncthreads();

        // prefetch tile j+1 (lands during this tile's compute)
        if (j < 63) {
            aptr += astep; sA = *(const uint4*)aptr;
            if (hasB) { bptr += 64; sB = *(const uint4*)bptr; }
        }

        // ---- S(j) from buf(stg)
        half8 kf[3];
        #pragma unroll
        for (int c = 0; c < 3; c++)
            kf[c] = *(const half8*)&ldsh[stg + (kh * 32 + m) * 64 + 8 * ((2 * c + half) ^ x7)];
        f32x16 S;
        #pragma unroll
        for (int i = 0; i < 16; i++) S[i] = 0.f;
        __builtin_amdgcn_s_setprio(1);
        S = MFMA16(kf[0], qa[0], S);
        S = MFMA16(kf[1], qa[1], S);
        S = MFMA16(kf[2], qa[2], S);
        __builtin_amdgcn_s_setprio(0);

        // ---- deferred PV(j-1) from buf(stgv): independent of exp(S) below,
        //      its MFMAs interleave with the exp burst and the S chain drain
        {
            const f16* Vb = &ldsh[stgv + 4096];
            half8 vf[2][2];
            #pragma unroll
            for (int c = 0; c < 2; c++) {
                vf[c][0] = *(const half8*)&Vb[m * 64        + 8 * ((4 * kh + 2 * c + half) ^ x7)];
                vf[c][1] = *(const half8*)&Vb[(32 + m) * 64 + 8 * ((4 * kh + 2 * c + half) ^ x7)];
            }
            __builtin_amdgcn_s_setprio(1);
            O0 = MFMA16(p0.h8, vf[0][0], O0);
            O1 = MFMA16(p0.h8, vf[0][1], O1);
            O0 = MFMA16(p1.h8, vf[1][0], O0);
            O1 = MFMA16(p1.h8, vf[1][1], O1);
            __builtin_amdgcn_s_setprio(0);
        }

        // ---- p = exp2(S(j))  (TRANS pipe; overlaps PV MFMAs above)
        #pragma unroll
        for (int g = 0; g < 4; g++) {
            p0.p2[g] = __builtin_amdgcn_cvt_pkrtz(EXP2F(S[2 * g]),     EXP2F(S[2 * g + 1]));
            p1.p2[g] = __builtin_amdgcn_cvt_pkrtz(EXP2F(S[8 + 2 * g]), EXP2F(S[9 + 2 * g]));
        }

        stgv = stg;
        stg = (stg == 16384) ? 0 : stg + 8192;
    }

    // ---- final PV (tile 63) from buf(stgv)
    {
        const f16* Vb = &ldsh[stgv + 4096];
        half8 vf[2][2];
        #pragma unroll
        for (int c = 0; c < 2; c++) {
            vf[c][0] = *(const half8*)&Vb[m * 64        + 8 * ((4 * kh + 2 * c + half) ^ x7)];
            vf[c][1] = *(const half8*)&Vb[(32 + m) * 64 + 8 * ((4 * kh + 2 * c + half) ^ x7)];
        }
        O0 = MFMA16(p0.h8, vf[0][0], O0);
        O1 = MFMA16(p0.h8, vf[0][1], O1);
        O0 = MFMA16(p1.h8, vf[1][0], O0);
        O1 = MFMA16(p1.h8, vf[1][1], O1);
    }

    // ---- combine key-halves (exact: unnormalized sums), normalize, store y
    __syncthreads();
    if (kh == 1) {
        #pragma unroll
        for (int reg = 0; reg < 16; reg++) {
            int row = 4 * half + (reg & 3) + 8 * (reg >> 2);
            ldsf[(qp * 32 + row) * 66 + m]      = O0[reg];
            ldsf[(qp * 32 + row) * 66 + 32 + m] = O1[reg];
        }
    }
    __syncthreads();
    if (kh == 0) {
        #pragma unroll
        for (int reg = 0; reg < 16; reg++) {
            int row = 4 * half + (reg & 3) + 8 * (reg >> 2);
            O0[reg] += ldsf[(qp * 32 + row) * 66 + m];
            O1[reg] += ldsf[(qp * 32 + row) * 66 + 32 + m];
        }
        #pragma unroll
        for (int reg = 0; reg < 16; reg++) {
            float l = __shfl(O1[reg], 8 + 32 * half, 64);
            float rinv = 1.0f / l;
            int row = 4 * half + (reg & 3) + 8 * (reg >> 2);
            f16* yr = y + ((size_t)b * SEQ + q0 + qp * 32 + row) * INNER + h * DHEAD;
            yr[m] = (f16)(O0[reg] * rinv);                 // d 0..31
            if (m < 8) yr[32 + m] = (f16)(O1[reg] * rinv); // d 32..39
        }
    }
}

// ---------------------------------------------------------------------------
// Output projection, fp16 MFMA: out = y @ Wout^T + bout, fp32 out.
// (r7 structure, verbatim)
// ---------------------------------------------------------------------------
#define ASTR 72

__global__ __launch_bounds__(256)
void out_proj_kernel(const f16* __restrict__ y, const f16* __restrict__ wouth,
                     const float* __restrict__ bout, float* __restrict__ out)
{
    __shared__ f16 lds[(128 + 64) * ASTR];
    f16* As = lds;
    f16* Bs = lds + 128 * ASTR;

    const int tid = threadIdx.x;
    const int m0 = blockIdx.y * 128;
    const int n0 = blockIdx.x * 64;
    const int wave = tid >> 6, lane = tid & 63, m = lane & 31, half = lane >> 5;

    f32x16 acc[2];
    #pragma unroll
    for (int i = 0; i < 16; i++) { acc[0][i] = 0.f; acc[1][i] = 0.f; }

    for (int k0 = 0; k0 < 320; k0 += 64) {
        __syncthreads();
        #pragma unroll
        for (int u = 0; u < 4; u++) {
            int idx = tid + 256 * u;
            int r = idx >> 3, c8 = idx & 7;
            *(uint4*)&As[r * ASTR + c8 * 8] =
                *(const uint4*)&y[(size_t)(m0 + r) * 320 + k0 + c8 * 8];
        }
        #pragma unroll
        for (int u = 0; u < 2; u++) {
            int idx = tid + 256 * u;
            int r = idx >> 3, c8 = idx & 7;
            *(uint4*)&Bs[r * ASTR + c8 * 8] =
                *(const uint4*)&wouth[(size_t)(n0 + r) * 320 + k0 + c8 * 8];
        }
        __syncthreads();
        #pragma unroll
        for (int c = 0; c < 4; c++) {
            half8 a  = *(const half8*)&As[(wave * 32 + m) * ASTR + c * 16 + half * 8];
            half8 b0 = *(const half8*)&Bs[m * ASTR + c * 16 + half * 8];
            half8 b1 = *(const half8*)&Bs[(32 + m) * ASTR + c * 16 + half * 8];
            acc[0] = MFMA16(a, b0, acc[0]);
            acc[1] = MFMA16(a, b1, acc[1]);
        }
    }

    #pragma unroll
    for (int nt = 0; nt < 2; nt++) {
        int n = n0 + nt * 32 + m;
        float bias = bout[n];
        #pragma unroll
        for (int reg = 0; reg < 16; reg++) {
            int crow = 4 * half + (reg & 3) + 8 * (reg >> 2);
            out[(size_t)(m0 + wave * 32 + crow) * 320 + n] = acc[nt][reg] + bias;
        }
    }
}

// ---------------------------------------------------------------------------
extern "C" void kernel_launch(void* const* d_in, const int* in_sizes, int n_in,
                              void* d_out, int out_size, void* d_ws, size_t ws_size,
                              hipStream_t stream)
{
    const float* x    = (const float*)d_in[0];
    const float* Wq   = (const float*)d_in[1];
    const float* Wk   = (const float*)d_in[2];
    const float* Wv   = (const float*)d_in[3];
    const float* Wout = (const float*)d_in[4];
    const float* bout = (const float*)d_in[5];
    float* out = (float*)d_out;

    unsigned char* ws = (unsigned char*)d_ws;
    f16* wh    = (f16*)(ws);                  //    614,400 B
    f16* wouth = (f16*)(ws +   614400);       //    204,800 B
    f16* qd    = (f16*)(ws +   819200);       //  5,242,880 B
    f16* kd    = (f16*)(ws +  6062080);       //  5,242,880 B
    f16* vtd   = (f16*)(ws + 11304960);       //  5,242,880 B
    f16* yd    = (f16*)(ws + 16547840);       //  5,242,880 B

    convert_kernel <<<400,          256, 0, stream>>>(Wq, Wk, Wv, Wout, wh, wouth);
    qkv_gemm_kernel<<<dim3(5, 128), 256, 0, stream>>>(x, wh, qd, kd, vtd);
    attn_kernel    <<<512,          512, 0, stream>>>(qd, kd, vtd, yd);
    out_proj_kernel<<<dim3(5, 64),  256, 0, stream>>>(yd, wouth, bout, out);
}